// Round 1
// baseline (413.030 us; speedup 1.0000x reference)
//
#include <hip/hip_runtime.h>
#include <cstdint>
#include <cstddef>

// ---------------- problem constants ----------------
constexpr int kLq = 128;        // query length
constexpr int kLd = 512;        // doc length
constexpr int kD  = 64;         // embed dim
constexpr int kB  = 128;        // 1 pos + 127 neg docs
constexpr int kC1 = 8;          // conv1 channels
constexpr int kC2 = 16;         // conv2 channels
constexpr int kH1R = 126;       // conv1 out rows (128-2)
constexpr int kH1C = 510;       // conv1 out cols (512-2)
constexpr int kTileC = 51;      // output cols per tile
constexpr int kNTiles = 10;     // 10*51 = 510
constexpr int kMCols = 53;      // kTileC + 2 input cols needed

// LDS pitches (floats)
constexpr int QT_PITCH = 132;   // query_t[d][q]: 64 x 132 (16B-aligned rows, bank stride 4)
constexpr int DS_PITCH = 68;    // doc_s[l][d]:  56 x 68  (16B-aligned rows)
constexpr int MS_PITCH = 56;    // m_s[q][l]:   128 x 56

// Branchless sorted-insert into descending top-K list.
// LEX=false: strict value compare (correct when idx processed ascending).
// LEX=true : (value desc, idx asc) lexicographic — order-independent.
template <int K, bool LEX>
__device__ __forceinline__ void topk_insert(float (&tv)[K], int (&ti)[K],
                                            float v, int idx) {
  bool gK = LEX ? ((v > tv[K - 1]) | ((v == tv[K - 1]) & (idx < ti[K - 1])))
                : (v > tv[K - 1]);
  if (!gK) return;
  bool g[K];
#pragma unroll
  for (int k = 0; k < K; ++k)
    g[k] = LEX ? ((v > tv[k]) | ((v == tv[k]) & (idx < ti[k]))) : (v > tv[k]);
#pragma unroll
  for (int k = K - 1; k >= 1; --k) {
    tv[k] = g[k - 1] ? tv[k - 1] : (g[k] ? v : tv[k]);
    ti[k] = g[k - 1] ? ti[k - 1] : (g[k] ? idx : ti[k]);
  }
  if (g[0]) { tv[0] = v; ti[0] = idx; }
}

// =====================================================================
// Kernel A: per (doc, 51-col tile): m = q.docT  -> conv1(3x3)+relu
//           -> top-8-of-126 rows per column (order kept)
//           -> pooled[b][c][slot][col]   (pitch 512)
// =====================================================================
__global__ __launch_bounds__(256, 2)
void convpool1_kernel(const float* __restrict__ query,
                      const float* __restrict__ pos_doc,
                      const float* __restrict__ neg_docs,
                      const float* __restrict__ c1w,
                      const float* __restrict__ c1b,
                      float* __restrict__ pooled) {
  __shared__ float q_t[64 * QT_PITCH];    // 33.8 KB, transposed [d][q]
  __shared__ float d_s[56 * DS_PITCH];    // 15.2 KB, [l_local][d]
  __shared__ float m_s[kLq * MS_PITCH];   // 28.7 KB, [q][l_local]

  const int tid  = threadIdx.x;
  const int tile = blockIdx.x;
  const int b    = blockIdx.y;
  const int l0g  = tile * kTileC;

  const float* doc =
      (b == 0) ? pos_doc : (neg_docs + (size_t)(b - 1) * kLd * kD);

  // ---- load query transposed: 2048 float4 global reads (coalesced) ----
  for (int e = tid; e < (kLq * kD) / 4; e += 256) {
    const float4 v = reinterpret_cast<const float4*>(query)[e];
    const int q  = e >> 4;          // 16 float4 per 64-elem row
    const int d0 = (e & 15) << 2;
    q_t[(d0 + 0) * QT_PITCH + q] = v.x;
    q_t[(d0 + 1) * QT_PITCH + q] = v.y;
    q_t[(d0 + 2) * QT_PITCH + q] = v.z;
    q_t[(d0 + 3) * QT_PITCH + q] = v.w;
  }
  // ---- load doc rows l0g..l0g+52; zero pad rows 53..55 ----
  for (int e = tid; e < 56 * 16; e += 256) {
    const int l  = e >> 4;
    const int d0 = (e & 15) << 2;
    float4 v = make_float4(0.f, 0.f, 0.f, 0.f);
    if (l < kMCols)
      v = reinterpret_cast<const float4*>(doc + (size_t)(l0g + l) * kD)[e & 15];
    *reinterpret_cast<float4*>(&d_s[l * DS_PITCH + d0]) = v;
  }
  __syncthreads();

  // ---- m[q][l] = sum_d query[q][d]*doc[l][d], 4q x 4l register blocks ----
  for (int u = tid; u < 32 * 14; u += 256) {
    const int q0 = (u & 31) << 2;
    const int l0 = (u >> 5) << 2;
    float acc[4][4] = {};
#pragma unroll 4
    for (int d = 0; d < kD; d += 4) {
      float4 qv[4];
#pragma unroll
      for (int j = 0; j < 4; ++j)
        qv[j] = *reinterpret_cast<const float4*>(&q_t[(d + j) * QT_PITCH + q0]);
      float4 dv[4];
#pragma unroll
      for (int li = 0; li < 4; ++li)
        dv[li] = *reinterpret_cast<const float4*>(&d_s[(l0 + li) * DS_PITCH + d]);
#pragma unroll
      for (int li = 0; li < 4; ++li) {
        const float4 w = dv[li];
        acc[0][li] += qv[0].x * w.x + qv[1].x * w.y + qv[2].x * w.z + qv[3].x * w.w;
        acc[1][li] += qv[0].y * w.x + qv[1].y * w.y + qv[2].y * w.z + qv[3].y * w.w;
        acc[2][li] += qv[0].z * w.x + qv[1].z * w.y + qv[2].z * w.z + qv[3].z * w.w;
        acc[3][li] += qv[0].w * w.x + qv[1].w * w.y + qv[2].w * w.z + qv[3].w * w.w;
      }
    }
#pragma unroll
    for (int qi = 0; qi < 4; ++qi)
      *reinterpret_cast<float4*>(&m_s[(q0 + qi) * MS_PITCH + l0]) =
          make_float4(acc[qi][0], acc[qi][1], acc[qi][2], acc[qi][3]);
  }
  __syncthreads();

  // ---- conv1(3x3)+bias+relu fused with top-8-of-126 row pool ----
  for (int p = tid; p < kC1 * kTileC; p += 256) {
    const int c = p / kTileC;
    const int j = p % kTileC;
    float w[9];
#pragma unroll
    for (int k = 0; k < 9; ++k) w[k] = c1w[c * 9 + k];
    const float bias = c1b[c];

    float tv[8]; int ti[8];
#pragma unroll
    for (int k = 0; k < 8; ++k) { tv[k] = -1.f; ti[k] = 0x7fffffff; }

    float acc01 = 0.f, s0_pend = 0.f;  // pipeline: S0(t-2)+S1(t-1), S0(t-1)
    for (int t = 0; t < kLq; ++t) {
      const float x0 = m_s[t * MS_PITCH + j];
      const float x1 = m_s[t * MS_PITCH + j + 1];
      const float x2 = m_s[t * MS_PITCH + j + 2];
      const float S0 = w[0] * x0 + w[1] * x1 + w[2] * x2;
      const float S1 = w[3] * x0 + w[4] * x1 + w[5] * x2;
      const float S2 = w[6] * x0 + w[7] * x1 + w[8] * x2;
      if (t >= 2) {
        const float v = fmaxf(bias + acc01 + S2, 0.f);
        topk_insert<8, false>(tv, ti, v, t - 2);  // ascending row idx
      }
      acc01 = s0_pend + S1;
      s0_pend = S0;
    }
    // write in original row order: slot = rank of ti (indices distinct)
    float* dst = pooled + (((size_t)b * kC1 + c) * 8) * 512 + (l0g + j);
#pragma unroll
    for (int k = 0; k < 8; ++k) {
      int slot = 0;
#pragma unroll
      for (int m = 0; m < 8; ++m) slot += (ti[m] < ti[k]);
      dst[(size_t)slot * 512] = tv[k];
    }
  }
}

// =====================================================================
// Kernel B: per doc: col-pool top-8-of-510 -> [8][8][8]; conv2+relu ->
// [16][7][7]; top-4 row & col pools -> [16][4][4]; FC1(relu); FC2(relu).
// =====================================================================
__global__ __launch_bounds__(256, 4)
void tail_kernel(const float* __restrict__ pooled,
                 const float* __restrict__ c2w, const float* __restrict__ c2b,
                 const float* __restrict__ l1w, const float* __restrict__ l1b,
                 const float* __restrict__ l2w, const float* __restrict__ l2b,
                 float* __restrict__ out) {
  __shared__ float mv[64][4][8];
  __shared__ int   mi[64][4][8];
  __shared__ float w2s[kC2 * kC1 * 4];
  __shared__ float b2s[kC2];
  __shared__ float h2in[kC1][8][8];
  __shared__ float h2o[kC2][7][7];
  __shared__ float h3[kC2][4][7];
  __shared__ __align__(16) float feat[256];
  __shared__ float zbuf[100];

  const int b = blockIdx.x, tid = threadIdx.x;

  // stage conv2 weights
  for (int e = tid; e < kC2 * kC1 * 4; e += 256) w2s[e] = c2w[e];
  if (tid < kC2) b2s[tid] = c2b[tid];

  // ---- step 1: per (c,row) top-8-of-510 cols, 4 lanes each ----
  {
    const int pair = tid >> 2, lane4 = tid & 3;
    const int c = pair >> 3, row = pair & 7;
    const float* src = pooled + (((size_t)b * kC1 + c) * 8 + row) * 512;
    float tv[8]; int ti[8];
#pragma unroll
    for (int k = 0; k < 8; ++k) { tv[k] = -1.f; ti[k] = 0x7fffffff; }
    for (int j = lane4; j < kH1C; j += 4)
      topk_insert<8, false>(tv, ti, src[j], j);  // ascending j per lane
#pragma unroll
    for (int k = 0; k < 8; ++k) { mv[pair][lane4][k] = tv[k]; mi[pair][lane4][k] = ti[k]; }
  }
  __syncthreads();
  if ((tid & 3) == 0) {
    const int pair = tid >> 2;
    const int c = pair >> 3, row = pair & 7;
    float tv[8]; int ti[8];
#pragma unroll
    for (int k = 0; k < 8; ++k) { tv[k] = -1.f; ti[k] = 0x7fffffff; }
#pragma unroll
    for (int li = 0; li < 4; ++li)
#pragma unroll
      for (int kk = 0; kk < 8; ++kk)
        topk_insert<8, true>(tv, ti, mv[pair][li][kk], mi[pair][li][kk]);
#pragma unroll
    for (int k = 0; k < 8; ++k) {
      int slot = 0;
#pragma unroll
      for (int m = 0; m < 8; ++m) slot += (ti[m] < ti[k]);
      h2in[c][row][slot] = tv[k];
    }
  }
  __syncthreads();

  // ---- step 2: conv2 2x2 (8->16) + relu ----
  for (int v = tid; v < kC2 * 49; v += 256) {
    const int c2 = v / 49;
    const int r  = (v % 49) / 7;
    const int j  = v % 7;
    float s = b2s[c2];
#pragma unroll
    for (int cin = 0; cin < kC1; ++cin) {
      const float* wp = &w2s[(c2 * kC1 + cin) * 4];
      s += wp[0] * h2in[cin][r][j]     + wp[1] * h2in[cin][r][j + 1];
      s += wp[2] * h2in[cin][r + 1][j] + wp[3] * h2in[cin][r + 1][j + 1];
    }
    h2o[c2][r][j] = fmaxf(s, 0.f);
  }
  __syncthreads();

  // ---- step 3: top-4-of-7 rows per (c2, j) ----
  for (int p = tid; p < kC2 * 7; p += 256) {
    const int c2 = p / 7, j = p % 7;
    float tv[4]; int ti[4];
#pragma unroll
    for (int k = 0; k < 4; ++k) { tv[k] = -1.f; ti[k] = 0x7fffffff; }
    for (int r = 0; r < 7; ++r) topk_insert<4, false>(tv, ti, h2o[c2][r][j], r);
#pragma unroll
    for (int k = 0; k < 4; ++k) {
      int slot = 0;
#pragma unroll
      for (int m = 0; m < 4; ++m) slot += (ti[m] < ti[k]);
      h3[c2][slot][j] = tv[k];
    }
  }
  __syncthreads();

  // ---- step 4: top-4-of-7 cols per (c2, r) -> feat[256] ----
  for (int p = tid; p < kC2 * 4; p += 256) {
    const int c2 = p >> 2, r = p & 3;
    float tv[4]; int ti[4];
#pragma unroll
    for (int k = 0; k < 4; ++k) { tv[k] = -1.f; ti[k] = 0x7fffffff; }
    for (int j = 0; j < 7; ++j) topk_insert<4, false>(tv, ti, h3[c2][r][j], j);
#pragma unroll
    for (int k = 0; k < 4; ++k) {
      int slot = 0;
#pragma unroll
      for (int m = 0; m < 4; ++m) slot += (ti[m] < ti[k]);
      feat[c2 * 16 + r * 4 + slot] = tv[k];
    }
  }
  __syncthreads();

  // ---- FC1: z = relu(feat @ W1^T + b1) ----
  for (int o = tid; o < 100; o += 256) {
    float s = l1b[o];
    const float4* wr = reinterpret_cast<const float4*>(l1w + (size_t)o * 256);
    const float4* fr = reinterpret_cast<const float4*>(feat);
    for (int i = 0; i < 64; ++i) {
      const float4 w = wr[i], f = fr[i];
      s += w.x * f.x + w.y * f.y + w.z * f.z + w.w * f.w;
    }
    zbuf[o] = fmaxf(s, 0.f);
  }
  __syncthreads();

  // ---- FC2: s = relu(z @ W2^T + b2), wave-0 reduce ----
  if (tid < 64) {
    float s = 0.f;
    for (int o = tid; o < 100; o += 64) s += zbuf[o] * l2w[o];
#pragma unroll
    for (int off = 32; off >= 1; off >>= 1) s += __shfl_down(s, off, 64);
    if (tid == 0) out[b] = fmaxf(s + l2b[0], 0.f);
  }
}

// =====================================================================
extern "C" void kernel_launch(void* const* d_in, const int* in_sizes, int n_in,
                              void* d_out, int out_size, void* d_ws,
                              size_t ws_size, hipStream_t stream) {
  const float* query    = (const float*)d_in[0];
  const float* pos_doc  = (const float*)d_in[1];
  const float* neg_docs = (const float*)d_in[2];
  const float* c1w      = (const float*)d_in[3];
  const float* c1b      = (const float*)d_in[4];
  const float* c2w      = (const float*)d_in[5];
  const float* c2b      = (const float*)d_in[6];
  const float* l1w      = (const float*)d_in[7];
  const float* l1b      = (const float*)d_in[8];
  const float* l2w      = (const float*)d_in[9];
  const float* l2b      = (const float*)d_in[10];
  float* out    = (float*)d_out;
  float* pooled = (float*)d_ws;  // [128][8][8][512] f32 = 16 MB

  dim3 gridA(kNTiles, kB);
  hipLaunchKernelGGL(convpool1_kernel, gridA, dim3(256), 0, stream,
                     query, pos_doc, neg_docs, c1w, c1b, pooled);
  hipLaunchKernelGGL(tail_kernel, dim3(kB), dim3(256), 0, stream,
                     pooled, c2w, c2b, l1w, l1b, l2w, l2b, out);
}

// Round 5
// 310.870 us; speedup vs baseline: 1.3286x; 1.3286x over previous
//
#include <hip/hip_runtime.h>
#include <cstdint>
#include <cstddef>

// ---------------- problem constants ----------------
constexpr int kLq = 128;        // query length
constexpr int kLd = 512;        // doc length
constexpr int kD  = 64;         // embed dim
constexpr int kB  = 128;        // 1 pos + 127 neg docs
constexpr int kC1 = 8;          // conv1 channels
constexpr int kC2 = 16;         // conv2 channels
constexpr int kH1C = 510;       // conv1 out cols (512-2)
constexpr int kTileC = 51;      // output cols per tile
constexpr int kNTiles = 10;     // 10*51 = 510
constexpr int kMCols = 53;      // kTileC + 2 input cols needed
constexpr int kNCand = kNTiles * 8;  // 80 candidates per (c,r) row

// LDS pitches (floats)
constexpr int QT_PITCH = 132;   // query_t[d][q]: 64 x 132
constexpr int DS_PITCH = 68;    // doc_s[l][d]:  56 x 68
constexpr int MS_PITCH = 57;    // m_s[q][l]:   128 x 57 (scalar stores, odd-ish pitch)

// Branchless sorted-insert into descending top-K list.
// LEX=false: strict value compare (correct when idx processed ascending).
// LEX=true : (value desc, idx asc) lexicographic — order-independent.
template <int K, bool LEX>
__device__ __forceinline__ void topk_insert(float (&tv)[K], int (&ti)[K],
                                            float v, int idx) {
  bool gK = LEX ? ((v > tv[K - 1]) | ((v == tv[K - 1]) & (idx < ti[K - 1])))
                : (v > tv[K - 1]);
  if (!gK) return;
  bool g[K];
#pragma unroll
  for (int k = 0; k < K; ++k)
    g[k] = LEX ? ((v > tv[k]) | ((v == tv[k]) & (idx < ti[k]))) : (v > tv[k]);
#pragma unroll
  for (int k = K - 1; k >= 1; --k) {
    tv[k] = g[k - 1] ? tv[k - 1] : (g[k] ? v : tv[k]);
    ti[k] = g[k - 1] ? ti[k - 1] : (g[k] ? idx : ti[k]);
  }
  if (g[0]) { tv[0] = v; ti[0] = idx; }
}

// =====================================================================
// Kernel A: per (doc, 51-col tile):
//   m = q.docT -> conv1(3x3)+relu -> top-8-of-126 rows per column
//   -> per-tile top-8-of-51 cols per (c, slot-row)
//   -> compact candidate lists candv/candi[b][c][r][tile*8+k] (idx-ascending)
// =====================================================================
__global__ __launch_bounds__(512, 4)
void convpool1_kernel(const float* __restrict__ query,
                      const float* __restrict__ pos_doc,
                      const float* __restrict__ neg_docs,
                      const float* __restrict__ c1w,
                      const float* __restrict__ c1b,
                      float* __restrict__ candv,
                      int* __restrict__ candi) {
  __shared__ float q_t[64 * QT_PITCH];    // 33.8 KB, transposed [d][q]
  __shared__ float d_s[56 * DS_PITCH];    // 15.2 KB, [l_local][d]
  __shared__ float m_s[kLq * MS_PITCH];   // 29.2 KB, [q][l_local]
  float* ps = q_t;                        // overlay after matmul: [8][8][52]

  const int tid  = threadIdx.x;
  const int tile = blockIdx.x;
  const int b    = blockIdx.y;
  const int l0g  = tile * kTileC;

  const float* doc =
      (b == 0) ? pos_doc : (neg_docs + (size_t)(b - 1) * kLd * kD);

  // ---- load query transposed. Lane->element mapping permuted so that
  // concurrent lanes write consecutive q (consecutive banks, conflict-free).
  {
    const float4* qf4 = reinterpret_cast<const float4*>(query);
    for (int e = tid; e < (kLq * kD) / 4; e += 512) {
      const int q  = e & 127;
      const int f4 = e >> 7;            // 0..15
      const float4 v = qf4[q * 16 + f4];
      const int d0 = f4 << 2;
      q_t[(d0 + 0) * QT_PITCH + q] = v.x;
      q_t[(d0 + 1) * QT_PITCH + q] = v.y;
      q_t[(d0 + 2) * QT_PITCH + q] = v.z;
      q_t[(d0 + 3) * QT_PITCH + q] = v.w;
    }
  }
  // ---- load doc rows l0g..l0g+52; zero pad rows 53..55 ----
  for (int e = tid; e < 56 * 16; e += 512) {
    const int l  = e >> 4;
    const int d0 = (e & 15) << 2;
    float4 v = make_float4(0.f, 0.f, 0.f, 0.f);
    if (l < kMCols)
      v = reinterpret_cast<const float4*>(doc + (size_t)(l0g + l) * kD)[e & 15];
    *reinterpret_cast<float4*>(&d_s[l * DS_PITCH + d0]) = v;
  }
  __syncthreads();

  // ---- m[q][l] = sum_d query[q][d]*doc[l][d], 4q x 4l register blocks ----
  if (tid < 32 * 14) {
    const int q0 = (tid & 31) << 2;
    const int l0 = (tid >> 5) << 2;
    float acc[4][4] = {};
#pragma unroll 4
    for (int d = 0; d < kD; d += 4) {
      float4 qv[4];
#pragma unroll
      for (int j = 0; j < 4; ++j)
        qv[j] = *reinterpret_cast<const float4*>(&q_t[(d + j) * QT_PITCH + q0]);
      float4 dv[4];
#pragma unroll
      for (int li = 0; li < 4; ++li)
        dv[li] = *reinterpret_cast<const float4*>(&d_s[(l0 + li) * DS_PITCH + d]);
#pragma unroll
      for (int li = 0; li < 4; ++li) {
        const float4 w = dv[li];
        acc[0][li] += qv[0].x * w.x + qv[1].x * w.y + qv[2].x * w.z + qv[3].x * w.w;
        acc[1][li] += qv[0].y * w.x + qv[1].y * w.y + qv[2].y * w.z + qv[3].y * w.w;
        acc[2][li] += qv[0].z * w.x + qv[1].z * w.y + qv[2].z * w.z + qv[3].z * w.w;
        acc[3][li] += qv[0].w * w.x + qv[1].w * w.y + qv[2].w * w.z + qv[3].w * w.w;
      }
    }
#pragma unroll
    for (int qi = 0; qi < 4; ++qi)
#pragma unroll
      for (int li = 0; li < 4; ++li)
        m_s[(q0 + qi) * MS_PITCH + (l0 + li)] = acc[qi][li];
  }
  __syncthreads();

  // ---- conv1(3x3)+bias+relu fused with top-8-of-126 row pool ----
  // (writes into ps, which overlays q_t — matmul is done with q_t)
  if (tid < kC1 * kTileC) {
    const int c = tid / kTileC;
    const int j = tid % kTileC;
    float w[9];
#pragma unroll
    for (int k = 0; k < 9; ++k) w[k] = c1w[c * 9 + k];
    const float bias = c1b[c];

    float tv[8]; int ti[8];
#pragma unroll
    for (int k = 0; k < 8; ++k) { tv[k] = -1.f; ti[k] = 0x7fffffff; }

    float acc01 = 0.f, s0_pend = 0.f;  // pipeline: S0(t-2)+S1(t-1), S0(t-1)
    for (int t = 0; t < kLq; ++t) {
      const float x0 = m_s[t * MS_PITCH + j];
      const float x1 = m_s[t * MS_PITCH + j + 1];
      const float x2 = m_s[t * MS_PITCH + j + 2];
      const float S0 = w[0] * x0 + w[1] * x1 + w[2] * x2;
      const float S1 = w[3] * x0 + w[4] * x1 + w[5] * x2;
      const float S2 = w[6] * x0 + w[7] * x1 + w[8] * x2;
      if (t >= 2) {
        const float v = fmaxf(bias + acc01 + S2, 0.f);
        topk_insert<8, false>(tv, ti, v, t - 2);  // ascending row idx
      }
      acc01 = s0_pend + S1;
      s0_pend = S0;
    }
    // write in original row order into LDS: ps[c][slot][j]
#pragma unroll
    for (int k = 0; k < 8; ++k) {
      int slot = 0;
#pragma unroll
      for (int m = 0; m < 8; ++m) slot += (ti[m] < ti[k]);
      ps[(c * 8 + slot) * 52 + j] = tv[k];
    }
  }
  __syncthreads();

  // ---- per-tile partial col-pool: top-8-of-51 per (c, slot-row) ----
  if (tid < 64) {
    const int g = tid;                 // g = c*8 + r
    float tv[8]; int ti[8];
#pragma unroll
    for (int k = 0; k < 8; ++k) { tv[k] = -1.f; ti[k] = 0x7fffffff; }
    for (int j = 0; j < kTileC; ++j)
      topk_insert<8, false>(tv, ti, ps[g * 52 + j], l0g + j);  // ascending idx
    float* cv = candv + ((size_t)b * 64 + g) * kNCand + tile * 8;
    int*   ci = candi + ((size_t)b * 64 + g) * kNCand + tile * 8;
#pragma unroll
    for (int k = 0; k < 8; ++k) {
      int slot = 0;
#pragma unroll
      for (int m = 0; m < 8; ++m) slot += (ti[m] < ti[k]);
      cv[slot] = tv[k];
      ci[slot] = ti[k];
    }
  }
}

// =====================================================================
// Kernel B: per doc: merge 80 candidates per (c,r) -> [8][8][8];
// conv2+relu -> [16][7][7]; top-4 row & col pools -> [16][4][4];
// FC1(relu); FC2(relu).
// =====================================================================
__global__ __launch_bounds__(256, 4)
void tail_kernel(const float* __restrict__ candv, const int* __restrict__ candi,
                 const float* __restrict__ c2w, const float* __restrict__ c2b,
                 const float* __restrict__ l1w, const float* __restrict__ l1b,
                 const float* __restrict__ l2w, const float* __restrict__ l2b,
                 float* __restrict__ out) {
  __shared__ float mv[64][4][8];
  __shared__ int   mi[64][4][8];
  __shared__ float w2s[kC2 * kC1 * 4];
  __shared__ float b2s[kC2];
  __shared__ float h2in[kC1][8][8];
  __shared__ float h2o[kC2][7][7];
  __shared__ float h3[kC2][4][7];
  __shared__ __align__(16) float feat[256];
  __shared__ float zbuf[100];

  const int b = blockIdx.x, tid = threadIdx.x;

  // stage conv2 weights
  for (int e = tid; e < kC2 * kC1 * 4; e += 256) w2s[e] = c2w[e];
  if (tid < kC2) b2s[tid] = c2b[tid];

  // ---- step 1: merge 80 idx-ascending candidates per (c,r), 4 lanes each ----
  {
    const int g = tid >> 2, lane4 = tid & 3;   // g = c*8 + r
    const float* cv = candv + ((size_t)b * 64 + g) * kNCand;
    const int*   ci = candi + ((size_t)b * 64 + g) * kNCand;
    float tv[8]; int ti[8];
#pragma unroll
    for (int k = 0; k < 8; ++k) { tv[k] = -1.f; ti[k] = 0x7fffffff; }
    for (int p = lane4; p < kNCand; p += 4)
      topk_insert<8, false>(tv, ti, cv[p], ci[p]);  // ascending idx per lane
#pragma unroll
    for (int k = 0; k < 8; ++k) { mv[g][lane4][k] = tv[k]; mi[g][lane4][k] = ti[k]; }
  }
  __syncthreads();
  if ((tid & 3) == 0) {
    const int g = tid >> 2;
    const int c = g >> 3, row = g & 7;
    float tv[8]; int ti[8];
#pragma unroll
    for (int k = 0; k < 8; ++k) { tv[k] = -1.f; ti[k] = 0x7fffffff; }
#pragma unroll
    for (int li = 0; li < 4; ++li)
#pragma unroll
      for (int kk = 0; kk < 8; ++kk)
        topk_insert<8, true>(tv, ti, mv[g][li][kk], mi[g][li][kk]);
#pragma unroll
    for (int k = 0; k < 8; ++k) {
      int slot = 0;
#pragma unroll
      for (int m = 0; m < 8; ++m) slot += (ti[m] < ti[k]);
      h2in[c][row][slot] = tv[k];
    }
  }
  __syncthreads();

  // ---- step 2: conv2 2x2 (8->16) + relu ----
  for (int v = tid; v < kC2 * 49; v += 256) {
    const int c2 = v / 49;
    const int r  = (v % 49) / 7;
    const int j  = v % 7;
    float s = b2s[c2];
#pragma unroll
    for (int cin = 0; cin < kC1; ++cin) {
      const float* wp = &w2s[(c2 * kC1 + cin) * 4];
      s += wp[0] * h2in[cin][r][j]     + wp[1] * h2in[cin][r][j + 1];
      s += wp[2] * h2in[cin][r + 1][j] + wp[3] * h2in[cin][r + 1][j + 1];
    }
    h2o[c2][r][j] = fmaxf(s, 0.f);
  }
  __syncthreads();

  // ---- step 3: top-4-of-7 rows per (c2, j) ----
  for (int p = tid; p < kC2 * 7; p += 256) {
    const int c2 = p / 7, j = p % 7;
    float tv[4]; int ti[4];
#pragma unroll
    for (int k = 0; k < 4; ++k) { tv[k] = -1.f; ti[k] = 0x7fffffff; }
    for (int r = 0; r < 7; ++r) topk_insert<4, false>(tv, ti, h2o[c2][r][j], r);
#pragma unroll
    for (int k = 0; k < 4; ++k) {
      int slot = 0;
#pragma unroll
      for (int m = 0; m < 4; ++m) slot += (ti[m] < ti[k]);
      h3[c2][slot][j] = tv[k];
    }
  }
  __syncthreads();

  // ---- step 4: top-4-of-7 cols per (c2, r) -> feat[256] ----
  for (int p = tid; p < kC2 * 4; p += 256) {
    const int c2 = p >> 2, r = p & 3;
    float tv[4]; int ti[4];
#pragma unroll
    for (int k = 0; k < 4; ++k) { tv[k] = -1.f; ti[k] = 0x7fffffff; }
    for (int j = 0; j < 7; ++j) topk_insert<4, false>(tv, ti, h3[c2][r][j], j);
#pragma unroll
    for (int k = 0; k < 4; ++k) {
      int slot = 0;
#pragma unroll
      for (int m = 0; m < 4; ++m) slot += (ti[m] < ti[k]);
      feat[c2 * 16 + r * 4 + slot] = tv[k];
    }
  }
  __syncthreads();

  // ---- FC1: z = relu(feat @ W1^T + b1) ----
  for (int o = tid; o < 100; o += 256) {
    float s = l1b[o];
    const float4* wr = reinterpret_cast<const float4*>(l1w + (size_t)o * 256);
    const float4* fr = reinterpret_cast<const float4*>(feat);
    for (int i = 0; i < 64; ++i) {
      const float4 w = wr[i], f = fr[i];
      s += w.x * f.x + w.y * f.y + w.z * f.z + w.w * f.w;
    }
    zbuf[o] = fmaxf(s, 0.f);
  }
  __syncthreads();

  // ---- FC2: s = relu(z @ W2^T + b2), wave-0 reduce ----
  if (tid < 64) {
    float s = 0.f;
    for (int o = tid; o < 100; o += 64) s += zbuf[o] * l2w[o];
#pragma unroll
    for (int off = 32; off >= 1; off >>= 1) s += __shfl_down(s, off, 64);
    if (tid == 0) out[b] = fmaxf(s + l2b[0], 0.f);
  }
}

// =====================================================================
extern "C" void kernel_launch(void* const* d_in, const int* in_sizes, int n_in,
                              void* d_out, int out_size, void* d_ws,
                              size_t ws_size, hipStream_t stream) {
  const float* query    = (const float*)d_in[0];
  const float* pos_doc  = (const float*)d_in[1];
  const float* neg_docs = (const float*)d_in[2];
  const float* c1w      = (const float*)d_in[3];
  const float* c1b      = (const float*)d_in[4];
  const float* c2w      = (const float*)d_in[5];
  const float* c2b      = (const float*)d_in[6];
  const float* l1w      = (const float*)d_in[7];
  const float* l1b      = (const float*)d_in[8];
  const float* l2w      = (const float*)d_in[9];
  const float* l2b      = (const float*)d_in[10];
  float* out = (float*)d_out;

  // workspace: candv [128][8][8][80] f32, candi same in int (2.62 MB each)
  float* candv = (float*)d_ws;
  int*   candi = (int*)((char*)d_ws + (size_t)kB * 64 * kNCand * sizeof(float));

  dim3 gridA(kNTiles, kB);
  hipLaunchKernelGGL(convpool1_kernel, gridA, dim3(512), 0, stream,
                     query, pos_doc, neg_docs, c1w, c1b, candv, candi);
  hipLaunchKernelGGL(tail_kernel, dim3(kB), dim3(256), 0, stream,
                     candv, candi, c2w, c2b, l1w, l1b, l2w, l2b, out);
}

// Round 6
// 270.815 us; speedup vs baseline: 1.5251x; 1.1479x over previous
//
#include <hip/hip_runtime.h>
#include <cstdint>
#include <cstddef>

// ---------------- problem constants ----------------
constexpr int kLq = 128;        // query length
constexpr int kLd = 512;        // doc length
constexpr int kD  = 64;         // embed dim
constexpr int kB  = 128;        // 1 pos + 127 neg docs
constexpr int kC1 = 8;          // conv1 channels
constexpr int kC2 = 16;         // conv2 channels
constexpr int kH1C = 510;       // conv1 out cols (512-2)
constexpr int kTileC = 51;      // output cols per tile
constexpr int kNTiles = 10;     // 10*51 = 510
constexpr int kMCols = 53;      // kTileC + 2 input cols needed
constexpr int kNCand = kNTiles * 8;  // 80 candidates per (c,r) row

// LDS pitches (floats)
constexpr int QT_PITCH = 132;   // query_t[d][q]: 64 x 132
constexpr int DS_PITCH = 68;    // doc_s[l][d]:  56 x 68
constexpr int MS_PITCH = 57;    // m_s[q][l]:   128 x 57

// LDS overlay offsets (floats). Staging (q_t,d_s) and m_s/ps are temporally
// disjoint: matmul reads staging -> barrier -> writes m_s over it.
constexpr int kQtOff = 0;                    // 64*132   = 8448
constexpr int kDsOff = 64 * QT_PITCH;        // 56*68    = 3808 -> end 12256
constexpr int kMsOff = 0;                    // 128*57   = 7296 (overlay)
constexpr int kPsOff = kLq * MS_PITCH;       // 8*8*52   = 3328 -> end 10624
constexpr int kLdsFloats = kDsOff + 56 * DS_PITCH;  // 12256 floats = 49,024 B

// Branchless sorted-insert into descending top-K list.
// LEX=false: strict value compare (correct when idx processed ascending).
// LEX=true : (value desc, idx asc) lexicographic — order-independent.
template <int K, bool LEX>
__device__ __forceinline__ void topk_insert(float (&tv)[K], int (&ti)[K],
                                            float v, int idx) {
  bool gK = LEX ? ((v > tv[K - 1]) | ((v == tv[K - 1]) & (idx < ti[K - 1])))
                : (v > tv[K - 1]);
  if (!gK) return;
  bool g[K];
#pragma unroll
  for (int k = 0; k < K; ++k)
    g[k] = LEX ? ((v > tv[k]) | ((v == tv[k]) & (idx < ti[k]))) : (v > tv[k]);
#pragma unroll
  for (int k = K - 1; k >= 1; --k) {
    tv[k] = g[k - 1] ? tv[k - 1] : (g[k] ? v : tv[k]);
    ti[k] = g[k - 1] ? ti[k - 1] : (g[k] ? idx : ti[k]);
  }
  if (g[0]) { tv[0] = v; ti[0] = idx; }
}

// =====================================================================
// Kernel A: per (doc, 51-col tile):
//   m = q.docT -> conv1(3x3)+relu -> top-8-of-126 rows per column
//   -> per-tile top-8-of-51 cols per (c, slot-row)
//   -> compact candidate lists candv/candi[b][c][r][tile*8+k] (idx-ascending)
// LDS overlay: 49.0 KB -> 3 blocks/CU (was 78.3 KB -> 2).
// =====================================================================
__global__ __launch_bounds__(512, 6)
void convpool1_kernel(const float* __restrict__ query,
                      const float* __restrict__ pos_doc,
                      const float* __restrict__ neg_docs,
                      const float* __restrict__ c1w,
                      const float* __restrict__ c1b,
                      float* __restrict__ candv,
                      int* __restrict__ candi) {
  __shared__ float lds[kLdsFloats];   // 49,024 B
  float* q_t = lds + kQtOff;          // [64][132] transposed [d][q]
  float* d_s = lds + kDsOff;          // [56][68]  [l_local][d]
  float* m_s = lds + kMsOff;          // [128][57] (overlays q_t after matmul)
  float* ps  = lds + kPsOff;          // [8][8][52] (overlays q_t tail/d_s head)

  const int tid  = threadIdx.x;
  const int tile = blockIdx.x;
  const int b    = blockIdx.y;
  const int l0g  = tile * kTileC;

  const float* doc =
      (b == 0) ? pos_doc : (neg_docs + (size_t)(b - 1) * kLd * kD);

  // ---- load query transposed. Lane->element mapping permuted so that
  // concurrent lanes write consecutive q (consecutive banks, conflict-free).
  {
    const float4* qf4 = reinterpret_cast<const float4*>(query);
    for (int e = tid; e < (kLq * kD) / 4; e += 512) {
      const int q  = e & 127;
      const int f4 = e >> 7;            // 0..15
      const float4 v = qf4[q * 16 + f4];
      const int d0 = f4 << 2;
      q_t[(d0 + 0) * QT_PITCH + q] = v.x;
      q_t[(d0 + 1) * QT_PITCH + q] = v.y;
      q_t[(d0 + 2) * QT_PITCH + q] = v.z;
      q_t[(d0 + 3) * QT_PITCH + q] = v.w;
    }
  }
  // ---- load doc rows l0g..l0g+52; zero pad rows 53..55 ----
  for (int e = tid; e < 56 * 16; e += 512) {
    const int l  = e >> 4;
    const int d0 = (e & 15) << 2;
    float4 v = make_float4(0.f, 0.f, 0.f, 0.f);
    if (l < kMCols)
      v = reinterpret_cast<const float4*>(doc + (size_t)(l0g + l) * kD)[e & 15];
    *reinterpret_cast<float4*>(&d_s[l * DS_PITCH + d0]) = v;
  }
  __syncthreads();

  // ---- m[q][l] = sum_d query[q][d]*doc[l][d], 4q x 4l register blocks ----
  float acc[4][4] = {};
  if (tid < 32 * 14) {
    const int q0 = (tid & 31) << 2;
    const int l0 = (tid >> 5) << 2;
#pragma unroll 4
    for (int d = 0; d < kD; d += 4) {
      float4 qv[4];
#pragma unroll
      for (int j = 0; j < 4; ++j)
        qv[j] = *reinterpret_cast<const float4*>(&q_t[(d + j) * QT_PITCH + q0]);
      float4 dv[4];
#pragma unroll
      for (int li = 0; li < 4; ++li)
        dv[li] = *reinterpret_cast<const float4*>(&d_s[(l0 + li) * DS_PITCH + d]);
#pragma unroll
      for (int li = 0; li < 4; ++li) {
        const float4 w = dv[li];
        acc[0][li] += qv[0].x * w.x + qv[1].x * w.y + qv[2].x * w.z + qv[3].x * w.w;
        acc[1][li] += qv[0].y * w.x + qv[1].y * w.y + qv[2].y * w.z + qv[3].y * w.w;
        acc[2][li] += qv[0].z * w.x + qv[1].z * w.y + qv[2].z * w.z + qv[3].z * w.w;
        acc[3][li] += qv[0].w * w.x + qv[1].w * w.y + qv[2].w * w.z + qv[3].w * w.w;
      }
    }
  }
  // all matmul READS of q_t/d_s must complete before m_s overlays them
  __syncthreads();
  if (tid < 32 * 14) {
    const int q0 = (tid & 31) << 2;
    const int l0 = (tid >> 5) << 2;
#pragma unroll
    for (int qi = 0; qi < 4; ++qi)
#pragma unroll
      for (int li = 0; li < 4; ++li)
        m_s[(q0 + qi) * MS_PITCH + (l0 + li)] = acc[qi][li];
  }
  __syncthreads();

  // ---- conv1(3x3)+bias+relu fused with top-8-of-126 row pool ----
  if (tid < kC1 * kTileC) {
    const int c = tid / kTileC;
    const int j = tid % kTileC;
    float w[9];
#pragma unroll
    for (int k = 0; k < 9; ++k) w[k] = c1w[c * 9 + k];
    const float bias = c1b[c];

    float tv[8]; int ti[8];
#pragma unroll
    for (int k = 0; k < 8; ++k) { tv[k] = -1.f; ti[k] = 0x7fffffff; }

    float acc01 = 0.f, s0_pend = 0.f;  // pipeline: S0(t-2)+S1(t-1), S0(t-1)
    for (int t = 0; t < kLq; ++t) {
      const float x0 = m_s[t * MS_PITCH + j];
      const float x1 = m_s[t * MS_PITCH + j + 1];
      const float x2 = m_s[t * MS_PITCH + j + 2];
      const float S0 = w[0] * x0 + w[1] * x1 + w[2] * x2;
      const float S1 = w[3] * x0 + w[4] * x1 + w[5] * x2;
      const float S2 = w[6] * x0 + w[7] * x1 + w[8] * x2;
      if (t >= 2) {
        const float v = fmaxf(bias + acc01 + S2, 0.f);
        topk_insert<8, false>(tv, ti, v, t - 2);  // ascending row idx
      }
      acc01 = s0_pend + S1;
      s0_pend = S0;
    }
    // write in original row order into LDS: ps[c][slot][j]
    // (ps region is disjoint from m_s reads still in flight on other threads)
#pragma unroll
    for (int k = 0; k < 8; ++k) {
      int slot = 0;
#pragma unroll
      for (int m = 0; m < 8; ++m) slot += (ti[m] < ti[k]);
      ps[(c * 8 + slot) * 52 + j] = tv[k];
    }
  }
  __syncthreads();

  // ---- per-tile partial col-pool: top-8-of-51 per (c, slot-row) ----
  if (tid < 64) {
    const int g = tid;                 // g = c*8 + r
    float tv[8]; int ti[8];
#pragma unroll
    for (int k = 0; k < 8; ++k) { tv[k] = -1.f; ti[k] = 0x7fffffff; }
    for (int j = 0; j < kTileC; ++j)
      topk_insert<8, false>(tv, ti, ps[g * 52 + j], l0g + j);  // ascending idx
    float* cv = candv + ((size_t)b * 64 + g) * kNCand + tile * 8;
    int*   ci = candi + ((size_t)b * 64 + g) * kNCand + tile * 8;
#pragma unroll
    for (int k = 0; k < 8; ++k) {
      int slot = 0;
#pragma unroll
      for (int m = 0; m < 8; ++m) slot += (ti[m] < ti[k]);
      cv[slot] = tv[k];
      ci[slot] = ti[k];
    }
  }
}

// =====================================================================
// Kernel B: per doc (512 thr): merge 80 candidates per (c,r) with 8 lanes
// + tournament -> [8][8][8]; conv2+relu -> [16][7][7]; top-4 pools ->
// [16][4][4]; FC1(relu); FC2(relu).
// =====================================================================
__global__ __launch_bounds__(512)
void tail_kernel(const float* __restrict__ candv, const int* __restrict__ candi,
                 const float* __restrict__ c2w, const float* __restrict__ c2b,
                 const float* __restrict__ l1w, const float* __restrict__ l1b,
                 const float* __restrict__ l2w, const float* __restrict__ l2b,
                 float* __restrict__ out) {
  __shared__ float mv[64][8][8];
  __shared__ int   mi[64][8][8];
  __shared__ float w2s[kC2 * kC1 * 4];
  __shared__ float b2s[kC2];
  __shared__ float h2in[kC1][8][8];
  __shared__ float h2o[kC2][7][7];
  __shared__ float h3[kC2][4][7];
  __shared__ __align__(16) float feat[256];
  __shared__ float zbuf[100];

  const int b = blockIdx.x, tid = threadIdx.x;

  // stage conv2 weights (512 elements, one per thread)
  if (tid < kC2 * kC1 * 4) w2s[tid] = c2w[tid];
  if (tid < kC2) b2s[tid] = c2b[tid];

  // ---- step 1: merge 80 idx-ascending candidates per (c,r), 8 lanes each ----
  const int g = tid >> 3, lane8 = tid & 7;   // g = c*8 + r
  float tv[8]; int ti[8];
#pragma unroll
  for (int k = 0; k < 8; ++k) { tv[k] = -1.f; ti[k] = 0x7fffffff; }
  {
    const float* cv = candv + ((size_t)b * 64 + g) * kNCand;
    const int*   ci = candi + ((size_t)b * 64 + g) * kNCand;
    for (int p = lane8; p < kNCand; p += 8)
      topk_insert<8, false>(tv, ti, cv[p], ci[p]);  // ascending idx per lane
#pragma unroll
    for (int k = 0; k < 8; ++k) { mv[g][lane8][k] = tv[k]; mi[g][lane8][k] = ti[k]; }
  }
  __syncthreads();

  // ---- tournament merge 8 -> 4 -> 2 -> 1 lists (lex: order-independent) ----
#pragma unroll
  for (int s = 4; s >= 1; s >>= 1) {
    if (lane8 < s) {
#pragma unroll
      for (int kk = 0; kk < 8; ++kk)
        topk_insert<8, true>(tv, ti, mv[g][lane8 + s][kk], mi[g][lane8 + s][kk]);
      if (s > 1) {
#pragma unroll
        for (int k = 0; k < 8; ++k) { mv[g][lane8][k] = tv[k]; mi[g][lane8][k] = ti[k]; }
      }
    }
    __syncthreads();
  }
  if (lane8 == 0) {
    const int c = g >> 3, row = g & 7;
#pragma unroll
    for (int k = 0; k < 8; ++k) {
      int slot = 0;
#pragma unroll
      for (int m = 0; m < 8; ++m) slot += (ti[m] < ti[k]);
      h2in[c][row][slot] = tv[k];
    }
  }
  __syncthreads();

  // ---- step 2: conv2 2x2 (8->16) + relu ----
  for (int v = tid; v < kC2 * 49; v += 512) {
    const int c2 = v / 49;
    const int r  = (v % 49) / 7;
    const int j  = v % 7;
    float s = b2s[c2];
#pragma unroll
    for (int cin = 0; cin < kC1; ++cin) {
      const float* wp = &w2s[(c2 * kC1 + cin) * 4];
      s += wp[0] * h2in[cin][r][j]     + wp[1] * h2in[cin][r][j + 1];
      s += wp[2] * h2in[cin][r + 1][j] + wp[3] * h2in[cin][r + 1][j + 1];
    }
    h2o[c2][r][j] = fmaxf(s, 0.f);
  }
  __syncthreads();

  // ---- step 3: top-4-of-7 rows per (c2, j) ----
  if (tid < kC2 * 7) {
    const int c2 = tid / 7, j = tid % 7;
    float tv4[4]; int ti4[4];
#pragma unroll
    for (int k = 0; k < 4; ++k) { tv4[k] = -1.f; ti4[k] = 0x7fffffff; }
    for (int r = 0; r < 7; ++r) topk_insert<4, false>(tv4, ti4, h2o[c2][r][j], r);
#pragma unroll
    for (int k = 0; k < 4; ++k) {
      int slot = 0;
#pragma unroll
      for (int m = 0; m < 4; ++m) slot += (ti4[m] < ti4[k]);
      h3[c2][slot][j] = tv4[k];
    }
  }
  __syncthreads();

  // ---- step 4: top-4-of-7 cols per (c2, r) -> feat[256] ----
  if (tid < kC2 * 4) {
    const int c2 = tid >> 2, r = tid & 3;
    float tv4[4]; int ti4[4];
#pragma unroll
    for (int k = 0; k < 4; ++k) { tv4[k] = -1.f; ti4[k] = 0x7fffffff; }
    for (int j = 0; j < 7; ++j) topk_insert<4, false>(tv4, ti4, h3[c2][r][j], j);
#pragma unroll
    for (int k = 0; k < 4; ++k) {
      int slot = 0;
#pragma unroll
      for (int m = 0; m < 4; ++m) slot += (ti4[m] < ti4[k]);
      feat[c2 * 16 + r * 4 + slot] = tv4[k];
    }
  }
  __syncthreads();

  // ---- FC1: z = relu(feat @ W1^T + b1) ----
  if (tid < 100) {
    const int o = tid;
    float s = l1b[o];
    const float4* wr = reinterpret_cast<const float4*>(l1w + (size_t)o * 256);
    const float4* fr = reinterpret_cast<const float4*>(feat);
    for (int i = 0; i < 64; ++i) {
      const float4 w = wr[i], f = fr[i];
      s += w.x * f.x + w.y * f.y + w.z * f.z + w.w * f.w;
    }
    zbuf[o] = fmaxf(s, 0.f);
  }
  __syncthreads();

  // ---- FC2: s = relu(z @ W2^T + b2), wave-0 reduce ----
  if (tid < 64) {
    float s = 0.f;
    for (int o = tid; o < 100; o += 64) s += zbuf[o] * l2w[o];
#pragma unroll
    for (int off = 32; off >= 1; off >>= 1) s += __shfl_down(s, off, 64);
    if (tid == 0) out[b] = fmaxf(s + l2b[0], 0.f);
  }
}

// =====================================================================
extern "C" void kernel_launch(void* const* d_in, const int* in_sizes, int n_in,
                              void* d_out, int out_size, void* d_ws,
                              size_t ws_size, hipStream_t stream) {
  const float* query    = (const float*)d_in[0];
  const float* pos_doc  = (const float*)d_in[1];
  const float* neg_docs = (const float*)d_in[2];
  const float* c1w      = (const float*)d_in[3];
  const float* c1b      = (const float*)d_in[4];
  const float* c2w      = (const float*)d_in[5];
  const float* c2b      = (const float*)d_in[6];
  const float* l1w      = (const float*)d_in[7];
  const float* l1b      = (const float*)d_in[8];
  const float* l2w      = (const float*)d_in[9];
  const float* l2b      = (const float*)d_in[10];
  float* out = (float*)d_out;

  // workspace: candv [128][8][8][80] f32, candi same in int (2.62 MB each)
  float* candv = (float*)d_ws;
  int*   candi = (int*)((char*)d_ws + (size_t)kB * 64 * kNCand * sizeof(float));

  dim3 gridA(kNTiles, kB);
  hipLaunchKernelGGL(convpool1_kernel, gridA, dim3(512), 0, stream,
                     query, pos_doc, neg_docs, c1w, c1b, candv, candi);
  hipLaunchKernelGGL(tail_kernel, dim3(kB), dim3(512), 0, stream,
                     candv, candi, c2w, c2b, l1w, l1b, l2w, l2b, out);
}

// Round 13
// 268.744 us; speedup vs baseline: 1.5369x; 1.0077x over previous
//
#include <hip/hip_runtime.h>
#include <cstdint>
#include <cstddef>

// ---------------- problem constants ----------------
constexpr int kLq = 128;        // query length
constexpr int kLd = 512;        // doc length
constexpr int kD  = 64;         // embed dim
constexpr int kB  = 128;        // 1 pos + 127 neg docs
constexpr int kC1 = 8;          // conv1 channels
constexpr int kC2 = 16;         // conv2 channels
constexpr int kH1C = 510;       // conv1 out cols (512-2)
constexpr int kTileC = 51;      // output cols per tile
constexpr int kNTiles = 10;     // 10*51 = 510
constexpr int kMCols = 53;      // kTileC + 2 input cols needed
constexpr int kNCand = kNTiles * 8;  // 80 candidates per (c,r) row

// LDS pitches (floats)
constexpr int QT_PITCH = 132;   // query_t[d][q]: 64 x 132
constexpr int DS_PITCH = 68;    // doc_s[l][d]:  56 x 68
constexpr int MS_PITCH = 57;    // m_s[q][l]:   128 x 57

// LDS overlay offsets (floats). Staging (q_t,d_s) and m_s/ps are temporally
// disjoint: matmul reads staging -> barrier -> writes m_s over it.
constexpr int kQtOff = 0;                    // 64*132   = 8448
constexpr int kDsOff = 64 * QT_PITCH;        // 56*68    = 3808 -> end 12256
constexpr int kMsOff = 0;                    // 128*57   = 7296 (overlay)
constexpr int kPsOff = kLq * MS_PITCH;       // 8*8*52   = 3328 -> end 10624
constexpr int kLdsFloats = kDsOff + 56 * DS_PITCH;  // 12256 floats = 49,024 B

// ---------------------------------------------------------------------
// Packed-key top-8. Values are post-ReLU (>= 0, never -0.0: exact
// cancellation yields +0.0 in round-to-nearest), so IEEE bits are
// monotone as u32. key = (bits(v)<<32) | ~idx gives u64-descending ==
// (value desc, idx asc) — jax.lax.top_k's earliest-index-wins order.
// Keys are UNIQUE (distinct idx), so a strict-'>' carry-down chain is a
// correct sorted insert: per level 1 v_cmp_gt_u64 + 4 v_cndmask.
// ---------------------------------------------------------------------
__device__ __forceinline__ uint64_t pack_key(float v, unsigned idx) {
  return ((uint64_t)__float_as_uint(v) << 32) | (uint32_t)(~idx);
}

template <int K>
__device__ __forceinline__ void topk_u64(uint64_t (&key)[K], uint64_t c) {
#pragma unroll
  for (int k = 0; k < K; ++k) {
    const bool g = c > key[k];
    const uint64_t hi = g ? c : key[k];
    c = g ? key[k] : c;
    key[k] = hi;
  }
}

// Branchless sorted-insert into descending top-K list (kernel B, verified
// round-6 semantics). LEX=false: strict value compare (idx-ascending scans).
// LEX=true: (value desc, idx asc) lexicographic — order-independent.
template <int K, bool LEX>
__device__ __forceinline__ void topk_insert(float (&tv)[K], int (&ti)[K],
                                            float v, int idx) {
  bool gK = LEX ? ((v > tv[K - 1]) | ((v == tv[K - 1]) & (idx < ti[K - 1])))
                : (v > tv[K - 1]);
  if (!gK) return;
  bool g[K];
#pragma unroll
  for (int k = 0; k < K; ++k)
    g[k] = LEX ? ((v > tv[k]) | ((v == tv[k]) & (idx < ti[k]))) : (v > tv[k]);
#pragma unroll
  for (int k = K - 1; k >= 1; --k) {
    tv[k] = g[k - 1] ? tv[k - 1] : (g[k] ? v : tv[k]);
    ti[k] = g[k - 1] ? ti[k - 1] : (g[k] ? idx : ti[k]);
  }
  if (g[0]) { tv[0] = v; ti[0] = idx; }
}

// =====================================================================
// Kernel A: per (doc, 51-col tile):
//   m = q.docT -> conv1(3x3)+relu -> top-8-of-126 rows per column
//   -> per-tile top-8-of-51 cols per (c, slot-row)
//   -> compact candidate lists candv/candi[b][c][r][tile*8+k] (idx-ascending)
// =====================================================================
__global__ __launch_bounds__(512, 6)
void convpool1_kernel(const float* __restrict__ query,
                      const float* __restrict__ pos_doc,
                      const float* __restrict__ neg_docs,
                      const float* __restrict__ c1w,
                      const float* __restrict__ c1b,
                      float* __restrict__ candv,
                      int* __restrict__ candi) {
  __shared__ float lds[kLdsFloats];   // 49,024 B
  float* q_t = lds + kQtOff;          // [64][132] transposed [d][q]
  float* d_s = lds + kDsOff;          // [56][68]  [l_local][d]
  float* m_s = lds + kMsOff;          // [128][57] (overlays q_t after matmul)
  float* ps  = lds + kPsOff;          // [8][8][52]

  const int tid  = threadIdx.x;
  const int tile = blockIdx.x;
  const int b    = blockIdx.y;
  const int l0g  = tile * kTileC;

  const float* doc =
      (b == 0) ? pos_doc : (neg_docs + (size_t)(b - 1) * kLd * kD);

  // ---- load query transposed (lanes write consecutive q -> consecutive
  // banks, conflict-free) ----
  {
    const float4* qf4 = reinterpret_cast<const float4*>(query);
    for (int e = tid; e < (kLq * kD) / 4; e += 512) {
      const int q  = e & 127;
      const int f4 = e >> 7;            // 0..15
      const float4 v = qf4[q * 16 + f4];
      const int d0 = f4 << 2;
      q_t[(d0 + 0) * QT_PITCH + q] = v.x;
      q_t[(d0 + 1) * QT_PITCH + q] = v.y;
      q_t[(d0 + 2) * QT_PITCH + q] = v.z;
      q_t[(d0 + 3) * QT_PITCH + q] = v.w;
    }
  }
  // ---- load doc rows l0g..l0g+52; zero pad rows 53..55 ----
  for (int e = tid; e < 56 * 16; e += 512) {
    const int l  = e >> 4;
    const int d0 = (e & 15) << 2;
    float4 v = make_float4(0.f, 0.f, 0.f, 0.f);
    if (l < kMCols)
      v = reinterpret_cast<const float4*>(doc + (size_t)(l0g + l) * kD)[e & 15];
    *reinterpret_cast<float4*>(&d_s[l * DS_PITCH + d0]) = v;
  }
  __syncthreads();

  // ---- m[q][l] = sum_d query[q][d]*doc[l][d], 4q x 4l register blocks ----
  float acc[4][4] = {};
  if (tid < 32 * 14) {
    const int q0 = (tid & 31) << 2;
    const int l0 = (tid >> 5) << 2;
#pragma unroll 4
    for (int d = 0; d < kD; d += 4) {
      float4 qv[4];
#pragma unroll
      for (int j = 0; j < 4; ++j)
        qv[j] = *reinterpret_cast<const float4*>(&q_t[(d + j) * QT_PITCH + q0]);
      float4 dv[4];
#pragma unroll
      for (int li = 0; li < 4; ++li)
        dv[li] = *reinterpret_cast<const float4*>(&d_s[(l0 + li) * DS_PITCH + d]);
#pragma unroll
      for (int li = 0; li < 4; ++li) {
        const float4 w = dv[li];
        acc[0][li] += qv[0].x * w.x + qv[1].x * w.y + qv[2].x * w.z + qv[3].x * w.w;
        acc[1][li] += qv[0].y * w.x + qv[1].y * w.y + qv[2].y * w.z + qv[3].y * w.w;
        acc[2][li] += qv[0].z * w.x + qv[1].z * w.y + qv[2].z * w.z + qv[3].z * w.w;
        acc[3][li] += qv[0].w * w.x + qv[1].w * w.y + qv[2].w * w.z + qv[3].w * w.w;
      }
    }
  }
  // all matmul READS of q_t/d_s must complete before m_s overlays them
  __syncthreads();
  if (tid < 32 * 14) {
    const int q0 = (tid & 31) << 2;
    const int l0 = (tid >> 5) << 2;
#pragma unroll
    for (int qi = 0; qi < 4; ++qi)
#pragma unroll
      for (int li = 0; li < 4; ++li)
        m_s[(q0 + qi) * MS_PITCH + (l0 + li)] = acc[qi][li];
  }
  __syncthreads();

  // ---- conv1(3x3)+bias+relu fused with top-8-of-126 row pool ----
  if (tid < kC1 * kTileC) {
    const int c = tid / kTileC;
    const int j = tid % kTileC;
    float w[9];
#pragma unroll
    for (int k = 0; k < 9; ++k) w[k] = c1w[c * 9 + k];
    const float bias = c1b[c];

    uint64_t key[8];
#pragma unroll
    for (int k = 0; k < 8; ++k) key[k] = 0;  // sentinel < any genuine key

    float acc01 = 0.f, s0_pend = 0.f;  // pipeline: S0(t-2)+S1(t-1), S0(t-1)
    for (int t = 0; t < kLq; ++t) {
      const float x0 = m_s[t * MS_PITCH + j];
      const float x1 = m_s[t * MS_PITCH + j + 1];
      const float x2 = m_s[t * MS_PITCH + j + 2];
      const float S0 = w[0] * x0 + w[1] * x1 + w[2] * x2;
      const float S1 = w[3] * x0 + w[4] * x1 + w[5] * x2;
      const float S2 = w[6] * x0 + w[7] * x1 + w[8] * x2;
      if (t >= 2) {
        const float v = fmaxf(bias + acc01 + S2, 0.f);
        topk_u64<8>(key, pack_key(v, (unsigned)(t - 2)));
      }
      acc01 = s0_pend + S1;
      s0_pend = S0;
    }
    // write in original row order into LDS: ps[c][slot][j]
    // slot = rank by idx asc = rank by low-word (~idx) desc
#pragma unroll
    for (int k = 0; k < 8; ++k) {
      const uint32_t lo_k = (uint32_t)key[k];
      int slot = 0;
#pragma unroll
      for (int m = 0; m < 8; ++m) slot += ((uint32_t)key[m] > lo_k);
      ps[(c * 8 + slot) * 52 + j] = __uint_as_float((uint32_t)(key[k] >> 32));
    }
  }
  __syncthreads();

  // ---- per-tile partial col-pool: top-8-of-51 per (c, slot-row) ----
  if (tid < 64) {
    const int g = tid;                 // g = c*8 + r
    uint64_t key[8];
#pragma unroll
    for (int k = 0; k < 8; ++k) key[k] = 0;
    for (int j = 0; j < kTileC; ++j)
      topk_u64<8>(key, pack_key(ps[g * 52 + j], (unsigned)(l0g + j)));
    float* cv = candv + ((size_t)b * 64 + g) * kNCand + tile * 8;
    int*   ci = candi + ((size_t)b * 64 + g) * kNCand + tile * 8;
#pragma unroll
    for (int k = 0; k < 8; ++k) {
      const uint32_t lo_k = (uint32_t)key[k];
      int slot = 0;
#pragma unroll
      for (int m = 0; m < 8; ++m) slot += ((uint32_t)key[m] > lo_k);
      cv[slot] = __uint_as_float((uint32_t)(key[k] >> 32));
      ci[slot] = (int)(~lo_k);
    }
  }
}

// =====================================================================
// Kernel B (round-6 verified version): per doc (512 thr): merge 80
// candidates per (c,r) with 8 lanes + tournament -> [8][8][8];
// conv2+relu -> [16][7][7]; top-4 pools -> [16][4][4]; FC1(relu); FC2.
// =====================================================================
__global__ __launch_bounds__(512)
void tail_kernel(const float* __restrict__ candv, const int* __restrict__ candi,
                 const float* __restrict__ c2w, const float* __restrict__ c2b,
                 const float* __restrict__ l1w, const float* __restrict__ l1b,
                 const float* __restrict__ l2w, const float* __restrict__ l2b,
                 float* __restrict__ out) {
  __shared__ float mv[64][8][8];
  __shared__ int   mi[64][8][8];
  __shared__ float w2s[kC2 * kC1 * 4];
  __shared__ float b2s[kC2];
  __shared__ float h2in[kC1][8][8];
  __shared__ float h2o[kC2][7][7];
  __shared__ float h3[kC2][4][7];
  __shared__ __align__(16) float feat[256];
  __shared__ float zbuf[100];

  const int b = blockIdx.x, tid = threadIdx.x;

  // stage conv2 weights (512 elements, one per thread)
  if (tid < kC2 * kC1 * 4) w2s[tid] = c2w[tid];
  if (tid < kC2) b2s[tid] = c2b[tid];

  // ---- step 1: merge 80 idx-ascending candidates per (c,r), 8 lanes each ----
  const int g = tid >> 3, lane8 = tid & 7;   // g = c*8 + r
  float tv[8]; int ti[8];
#pragma unroll
  for (int k = 0; k < 8; ++k) { tv[k] = -1.f; ti[k] = 0x7fffffff; }
  {
    const float* cv = candv + ((size_t)b * 64 + g) * kNCand;
    const int*   ci = candi + ((size_t)b * 64 + g) * kNCand;
    for (int p = lane8; p < kNCand; p += 8)
      topk_insert<8, false>(tv, ti, cv[p], ci[p]);  // ascending idx per lane
#pragma unroll
    for (int k = 0; k < 8; ++k) { mv[g][lane8][k] = tv[k]; mi[g][lane8][k] = ti[k]; }
  }
  __syncthreads();

  // ---- tournament merge 8 -> 4 -> 2 -> 1 lists (lex: order-independent) ----
#pragma unroll
  for (int s = 4; s >= 1; s >>= 1) {
    if (lane8 < s) {
#pragma unroll
      for (int kk = 0; kk < 8; ++kk)
        topk_insert<8, true>(tv, ti, mv[g][lane8 + s][kk], mi[g][lane8 + s][kk]);
      if (s > 1) {
#pragma unroll
        for (int k = 0; k < 8; ++k) { mv[g][lane8][k] = tv[k]; mi[g][lane8][k] = ti[k]; }
      }
    }
    __syncthreads();
  }
  if (lane8 == 0) {
    const int c = g >> 3, row = g & 7;
#pragma unroll
    for (int k = 0; k < 8; ++k) {
      int slot = 0;
#pragma unroll
      for (int m = 0; m < 8; ++m) slot += (ti[m] < ti[k]);
      h2in[c][row][slot] = tv[k];
    }
  }
  __syncthreads();

  // ---- step 2: conv2 2x2 (8->16) + relu ----
  for (int v = tid; v < kC2 * 49; v += 512) {
    const int c2 = v / 49;
    const int r  = (v % 49) / 7;
    const int j  = v % 7;
    float s = b2s[c2];
#pragma unroll
    for (int cin = 0; cin < kC1; ++cin) {
      const float* wp = &w2s[(c2 * kC1 + cin) * 4];
      s += wp[0] * h2in[cin][r][j]     + wp[1] * h2in[cin][r][j + 1];
      s += wp[2] * h2in[cin][r + 1][j] + wp[3] * h2in[cin][r + 1][j + 1];
    }
    h2o[c2][r][j] = fmaxf(s, 0.f);
  }
  __syncthreads();

  // ---- step 3: top-4-of-7 rows per (c2, j) ----
  if (tid < kC2 * 7) {
    const int c2 = tid / 7, j = tid % 7;
    float tv4[4]; int ti4[4];
#pragma unroll
    for (int k = 0; k < 4; ++k) { tv4[k] = -1.f; ti4[k] = 0x7fffffff; }
    for (int r = 0; r < 7; ++r) topk_insert<4, false>(tv4, ti4, h2o[c2][r][j], r);
#pragma unroll
    for (int k = 0; k < 4; ++k) {
      int slot = 0;
#pragma unroll
      for (int m = 0; m < 4; ++m) slot += (ti4[m] < ti4[k]);
      h3[c2][slot][j] = tv4[k];
    }
  }
  __syncthreads();

  // ---- step 4: top-4-of-7 cols per (c2, r) -> feat[256] ----
  if (tid < kC2 * 4) {
    const int c2 = tid >> 2, r = tid & 3;
    float tv4[4]; int ti4[4];
#pragma unroll
    for (int k = 0; k < 4; ++k) { tv4[k] = -1.f; ti4[k] = 0x7fffffff; }
    for (int j = 0; j < 7; ++j) topk_insert<4, false>(tv4, ti4, h3[c2][r][j], j);
#pragma unroll
    for (int k = 0; k < 4; ++k) {
      int slot = 0;
#pragma unroll
      for (int m = 0; m < 4; ++m) slot += (ti4[m] < ti4[k]);
      feat[c2 * 16 + r * 4 + slot] = tv4[k];
    }
  }
  __syncthreads();

  // ---- FC1: z = relu(feat @ W1^T + b1) ----
  if (tid < 100) {
    const int o = tid;
    float s = l1b[o];
    const float4* wr = reinterpret_cast<const float4*>(l1w + (size_t)o * 256);
    const float4* fr = reinterpret_cast<const float4*>(feat);
    for (int i = 0; i < 64; ++i) {
      const float4 w = wr[i], f = fr[i];
      s += w.x * f.x + w.y * f.y + w.z * f.z + w.w * f.w;
    }
    zbuf[o] = fmaxf(s, 0.f);
  }
  __syncthreads();

  // ---- FC2: s = relu(z @ W2^T + b2), wave-0 reduce ----
  if (tid < 64) {
    float s = 0.f;
    for (int o = tid; o < 100; o += 64) s += zbuf[o] * l2w[o];
#pragma unroll
    for (int off = 32; off >= 1; off >>= 1) s += __shfl_down(s, off, 64);
    if (tid == 0) out[b] = fmaxf(s + l2b[0], 0.f);
  }
}

// =====================================================================
extern "C" void kernel_launch(void* const* d_in, const int* in_sizes, int n_in,
                              void* d_out, int out_size, void* d_ws,
                              size_t ws_size, hipStream_t stream) {
  const float* query    = (const float*)d_in[0];
  const float* pos_doc  = (const float*)d_in[1];
  const float* neg_docs = (const float*)d_in[2];
  const float* c1w      = (const float*)d_in[3];
  const float* c1b      = (const float*)d_in[4];
  const float* c2w      = (const float*)d_in[5];
  const float* c2b      = (const float*)d_in[6];
  const float* l1w      = (const float*)d_in[7];
  const float* l1b      = (const float*)d_in[8];
  const float* l2w      = (const float*)d_in[9];
  const float* l2b      = (const float*)d_in[10];
  float* out = (float*)d_out;

  // workspace: candv [128][8][8][80] f32, candi same in int (2.62 MB each)
  float* candv = (float*)d_ws;
  int*   candi = (int*)((char*)d_ws + (size_t)kB * 64 * kNCand * sizeof(float));

  dim3 gridA(kNTiles, kB);
  hipLaunchKernelGGL(convpool1_kernel, gridA, dim3(512), 0, stream,
                     query, pos_doc, neg_docs, c1w, c1b, candv, candi);
  hipLaunchKernelGGL(tail_kernel, dim3(kB), dim3(512), 0, stream,
                     candv, candi, c2w, c2b, l1w, l1b, l2w, l2b, out);
}